// Round 1
// baseline (373.652 us; speedup 1.0000x reference)
//
#include <hip/hip_runtime.h>

// CenterLoss: loss = main * (1 + 1/distocen) / 2 / B
//   main    = sum_b ||feat_b - centers[lab_b]||^2
//   distocen= sum_b ||feat_b - centers[(lab+1)%3]||^2 + ||feat_b - centers[(lab+2)%3]||^2
// Key identity: main + distocen = sum_b sum_{c in 0..2} ||feat_b - centers[c]||^2  (label-independent)
// -> accumulate just (main, total3); finalize on 1 thread.

constexpr int BATCH = 32768;
constexpr int FEAT = 2048;
constexpr int FEAT4 = FEAT / 4;      // 512 float4 per row
constexpr int BLOCKS = 2048;         // 2048*256 = 524288 threads; 32 float4/thread
constexpr int TPB = 256;

__global__ __launch_bounds__(TPB) void cl_main_kernel(
    const float4* __restrict__ feat4,
    const int* __restrict__ label,
    const float4* __restrict__ cent4,
    float* __restrict__ accum)       // accum[0]=main, accum[1]=total3
{
    const int total = BATCH * FEAT4; // 16,777,216
    int idx = blockIdx.x * TPB + threadIdx.x;
    const int stride = gridDim.x * TPB;

    float m_acc = 0.f;
    float t_acc = 0.f;

    for (; idx < total; idx += stride) {
        const int b = idx >> 9;      // /FEAT4
        const int d = idx & 511;     // %FEAT4
        const float4 f  = feat4[idx];
        const float4 c0 = cent4[d];
        const float4 c1 = cent4[FEAT4 + d];
        const float4 c2 = cent4[2 * FEAT4 + d];
        const int l = label[b];

        float ex, ey, ez, ew;
        ex = f.x - c0.x; ey = f.y - c0.y; ez = f.z - c0.z; ew = f.w - c0.w;
        const float s0 = ex*ex + ey*ey + ez*ez + ew*ew;
        ex = f.x - c1.x; ey = f.y - c1.y; ez = f.z - c1.z; ew = f.w - c1.w;
        const float s1 = ex*ex + ey*ey + ez*ez + ew*ew;
        ex = f.x - c2.x; ey = f.y - c2.y; ez = f.z - c2.z; ew = f.w - c2.w;
        const float s2 = ex*ex + ey*ey + ez*ez + ew*ew;

        t_acc += s0 + s1 + s2;
        // branchless label select (labels are wave-mostly-uniform anyway)
        const float sm = (l == 0) ? s0 : ((l == 1) ? s1 : s2);
        m_acc += sm;
    }

    // 64-lane wave reduction
    #pragma unroll
    for (int off = 32; off > 0; off >>= 1) {
        m_acc += __shfl_down(m_acc, off, 64);
        t_acc += __shfl_down(t_acc, off, 64);
    }

    __shared__ float sm_red[TPB / 64];
    __shared__ float st_red[TPB / 64];
    const int wave = threadIdx.x >> 6;
    const int lane = threadIdx.x & 63;
    if (lane == 0) { sm_red[wave] = m_acc; st_red[wave] = t_acc; }
    __syncthreads();
    if (threadIdx.x == 0) {
        float M = 0.f, T = 0.f;
        #pragma unroll
        for (int w = 0; w < TPB / 64; ++w) { M += sm_red[w]; T += st_red[w]; }
        atomicAdd(&accum[0], M);   // device-scope by default on CDNA
        atomicAdd(&accum[1], T);
    }
}

__global__ void cl_final_kernel(const float* __restrict__ accum,
                                float* __restrict__ out)
{
    const float m = accum[0];
    const float dist = accum[1] - m;   // = distocen
    out[0] = m * (1.0f + 1.0f / dist) * 0.5f / (float)BATCH;
}

extern "C" void kernel_launch(void* const* d_in, const int* in_sizes, int n_in,
                              void* d_out, int out_size, void* d_ws, size_t ws_size,
                              hipStream_t stream) {
    const float4* feat    = (const float4*)d_in[0];
    const int*    label   = (const int*)d_in[1];
    const float4* centers = (const float4*)d_in[2];
    float* out   = (float*)d_out;
    float* accum = (float*)d_ws;     // 2 floats of scratch; ws poisoned 0xAA -> must zero

    hipMemsetAsync(accum, 0, 2 * sizeof(float), stream);  // graph-capture safe
    cl_main_kernel<<<BLOCKS, TPB, 0, stream>>>(feat, label, centers, accum);
    cl_final_kernel<<<1, 1, 0, stream>>>(accum, out);
}

// Round 3
// 347.089 us; speedup vs baseline: 1.0765x; 1.0765x over previous
//
#include <hip/hip_runtime.h>

// CenterLoss: loss = main * (1 + 1/distocen) / 2 / B
//   main + distocen = sum_b sum_{c=0..2} ||feat_b - centers[c]||^2  (label-independent)
// -> accumulate (main, total3) only; finalize on 1 thread.
//
// R3 = R2 with the nontemporal load done through a native ext_vector float4
// (clang's builtin rejects HIP_vector_type). Column-persistent threads:
// each thread owns one float4 column d, centers live in 12 registers,
// 1 global load per iteration.

typedef float fvec4 __attribute__((ext_vector_type(4)));

constexpr int BATCH  = 32768;
constexpr int FEAT4  = 512;            // 2048 floats / 4
constexpr int TPB    = 512;            // one block spans a full row of float4 columns
constexpr int BLOCKS = 1024;
constexpr int ROWS   = BATCH / BLOCKS; // 32 rows per block

__global__ __launch_bounds__(TPB) void cl_main_kernel(
    const fvec4* __restrict__ feat4,
    const int* __restrict__ label,
    const fvec4* __restrict__ cent4,
    float* __restrict__ accum)          // accum[0]=main, accum[1]=total3
{
    const int d = threadIdx.x;          // fixed float4 column for this thread

    // centers resident in registers for the whole kernel
    const fvec4 c0 = cent4[d];
    const fvec4 c1 = cent4[FEAT4 + d];
    const fvec4 c2 = cent4[2 * FEAT4 + d];

    // stage this block's 32 labels in LDS (read once from global)
    __shared__ int slab[ROWS];
    const int b0 = blockIdx.x * ROWS;
    if (threadIdx.x < ROWS) slab[threadIdx.x] = label[b0 + threadIdx.x];
    __syncthreads();

    float m_acc = 0.f, t_acc = 0.f;
    const fvec4* fp = feat4 + (size_t)b0 * FEAT4 + d;

    #pragma unroll 4
    for (int r = 0; r < ROWS; ++r) {
        const fvec4 f = __builtin_nontemporal_load(&fp[(size_t)r * FEAT4]);
        const int l = slab[r];          // wave-uniform LDS broadcast

        fvec4 e0 = f - c0;
        fvec4 e1 = f - c1;
        fvec4 e2 = f - c2;
        const float s0 = e0.x*e0.x + e0.y*e0.y + e0.z*e0.z + e0.w*e0.w;
        const float s1 = e1.x*e1.x + e1.y*e1.y + e1.z*e1.z + e1.w*e1.w;
        const float s2 = e2.x*e2.x + e2.y*e2.y + e2.z*e2.z + e2.w*e2.w;

        t_acc += s0 + s1 + s2;
        m_acc += (l == 0) ? s0 : ((l == 1) ? s1 : s2);
    }

    // 64-lane wave reduction
    #pragma unroll
    for (int off = 32; off > 0; off >>= 1) {
        m_acc += __shfl_down(m_acc, off, 64);
        t_acc += __shfl_down(t_acc, off, 64);
    }

    __shared__ float sm_red[TPB / 64];
    __shared__ float st_red[TPB / 64];
    const int wave = threadIdx.x >> 6;
    const int lane = threadIdx.x & 63;
    if (lane == 0) { sm_red[wave] = m_acc; st_red[wave] = t_acc; }
    __syncthreads();
    if (threadIdx.x == 0) {
        float M = 0.f, T = 0.f;
        #pragma unroll
        for (int w = 0; w < TPB / 64; ++w) { M += sm_red[w]; T += st_red[w]; }
        atomicAdd(&accum[0], M);        // device-scope by default on CDNA
        atomicAdd(&accum[1], T);
    }
}

__global__ void cl_final_kernel(const float* __restrict__ accum,
                                float* __restrict__ out)
{
    const float m = accum[0];
    const float dist = accum[1] - m;    // = distocen
    out[0] = m * (1.0f + 1.0f / dist) * 0.5f / (float)BATCH;
}

extern "C" void kernel_launch(void* const* d_in, const int* in_sizes, int n_in,
                              void* d_out, int out_size, void* d_ws, size_t ws_size,
                              hipStream_t stream) {
    const fvec4* feat    = (const fvec4*)d_in[0];
    const int*   label   = (const int*)d_in[1];
    const fvec4* centers = (const fvec4*)d_in[2];
    float* out   = (float*)d_out;
    float* accum = (float*)d_ws;        // 2 floats scratch; ws poisoned 0xAA -> zero it

    (void)hipMemsetAsync(accum, 0, 2 * sizeof(float), stream);
    cl_main_kernel<<<BLOCKS, TPB, 0, stream>>>(feat, label, centers, accum);
    cl_final_kernel<<<1, 1, 0, stream>>>(accum, out);
}

// Round 4
// 335.169 us; speedup vs baseline: 1.1148x; 1.0356x over previous
//
#include <hip/hip_runtime.h>

// CenterLoss: loss = main * (1 + 1/distocen) / 2 / B
//   main + distocen = sum_b sum_{c=0..2} ||feat_b - centers[c]||^2  (label-independent)
// -> accumulate (main, total3) only.
//
// R4: drop memset + atomics. Each block writes its (main, total3) partial to
// its own d_ws slot (unconditional write -> no init needed on poisoned ws),
// then a single 1-block kernel reduces 1024 partials and finalizes.
// Graph: 2 dispatches instead of 3.

typedef float fvec4 __attribute__((ext_vector_type(4)));
typedef float fvec2 __attribute__((ext_vector_type(2)));

constexpr int BATCH  = 32768;
constexpr int FEAT4  = 512;            // 2048 floats / 4
constexpr int TPB    = 512;            // one block spans a full row of float4 columns
constexpr int BLOCKS = 1024;
constexpr int ROWS   = BATCH / BLOCKS; // 32 rows per block

__global__ __launch_bounds__(TPB) void cl_main_kernel(
    const fvec4* __restrict__ feat4,
    const int* __restrict__ label,
    const fvec4* __restrict__ cent4,
    fvec2* __restrict__ partial)        // partial[blk] = (main, total3)
{
    const int d = threadIdx.x;          // fixed float4 column for this thread

    // centers resident in registers for the whole kernel
    const fvec4 c0 = cent4[d];
    const fvec4 c1 = cent4[FEAT4 + d];
    const fvec4 c2 = cent4[2 * FEAT4 + d];

    // stage this block's 32 labels in LDS (read once from global)
    __shared__ int slab[ROWS];
    const int b0 = blockIdx.x * ROWS;
    if (threadIdx.x < ROWS) slab[threadIdx.x] = label[b0 + threadIdx.x];
    __syncthreads();

    float m_acc = 0.f, t_acc = 0.f;
    const fvec4* fp = feat4 + (size_t)b0 * FEAT4 + d;

    #pragma unroll 4
    for (int r = 0; r < ROWS; ++r) {
        const fvec4 f = __builtin_nontemporal_load(&fp[(size_t)r * FEAT4]);
        const int l = slab[r];          // wave-uniform LDS broadcast

        fvec4 e0 = f - c0;
        fvec4 e1 = f - c1;
        fvec4 e2 = f - c2;
        const float s0 = e0.x*e0.x + e0.y*e0.y + e0.z*e0.z + e0.w*e0.w;
        const float s1 = e1.x*e1.x + e1.y*e1.y + e1.z*e1.z + e1.w*e1.w;
        const float s2 = e2.x*e2.x + e2.y*e2.y + e2.z*e2.z + e2.w*e2.w;

        t_acc += s0 + s1 + s2;
        m_acc += (l == 0) ? s0 : ((l == 1) ? s1 : s2);
    }

    // 64-lane wave reduction
    #pragma unroll
    for (int off = 32; off > 0; off >>= 1) {
        m_acc += __shfl_down(m_acc, off, 64);
        t_acc += __shfl_down(t_acc, off, 64);
    }

    __shared__ float sm_red[TPB / 64];
    __shared__ float st_red[TPB / 64];
    const int wave = threadIdx.x >> 6;
    const int lane = threadIdx.x & 63;
    if (lane == 0) { sm_red[wave] = m_acc; st_red[wave] = t_acc; }
    __syncthreads();
    if (threadIdx.x == 0) {
        float M = 0.f, T = 0.f;
        #pragma unroll
        for (int w = 0; w < TPB / 64; ++w) { M += sm_red[w]; T += st_red[w]; }
        fvec2 p; p.x = M; p.y = T;
        partial[blockIdx.x] = p;        // own slot, no atomics/init needed
    }
}

__global__ __launch_bounds__(512) void cl_final_kernel(
    const fvec2* __restrict__ partial,
    float* __restrict__ out)
{
    // 1024 partial pairs; 512 threads read 2 each
    const int t = threadIdx.x;
    fvec2 a = partial[t];
    fvec2 b = partial[t + 512];
    float m_acc = a.x + b.x;
    float t_acc = a.y + b.y;

    #pragma unroll
    for (int off = 32; off > 0; off >>= 1) {
        m_acc += __shfl_down(m_acc, off, 64);
        t_acc += __shfl_down(t_acc, off, 64);
    }

    __shared__ float sm_red[8];
    __shared__ float st_red[8];
    const int wave = t >> 6;
    const int lane = t & 63;
    if (lane == 0) { sm_red[wave] = m_acc; st_red[wave] = t_acc; }
    __syncthreads();
    if (t == 0) {
        float M = 0.f, T = 0.f;
        #pragma unroll
        for (int w = 0; w < 8; ++w) { M += sm_red[w]; T += st_red[w]; }
        const float dist = T - M;       // = distocen
        out[0] = M * (1.0f + 1.0f / dist) * 0.5f / (float)BATCH;
    }
}

extern "C" void kernel_launch(void* const* d_in, const int* in_sizes, int n_in,
                              void* d_out, int out_size, void* d_ws, size_t ws_size,
                              hipStream_t stream) {
    const fvec4* feat    = (const fvec4*)d_in[0];
    const int*   label   = (const int*)d_in[1];
    const fvec4* centers = (const fvec4*)d_in[2];
    float* out     = (float*)d_out;
    fvec2* partial = (fvec2*)d_ws;      // 1024 * 8 B = 8 KiB of scratch

    cl_main_kernel<<<BLOCKS, TPB, 0, stream>>>(feat, label, centers, partial);
    cl_final_kernel<<<1, 512, 0, stream>>>(partial, out);
}